// Round 10
// baseline (8230.301 us; speedup 1.0000x reference)
//
#include <hip/hip_runtime.h>
#include <math.h>

typedef float vf4 __attribute__((ext_vector_type(4)));

// Problem dims (fixed by reference)
constexpr int T  = 512;
constexpr int BB = 64;    // batch
constexpr int II = 256;   // input
constexpr int HH = 512;   // hidden

// d_out layout (floats): out[B,T,H] | s[2,B,H] | h[2,B,H] | c[2,B,H]
constexpr int SOFF = BB * T * HH;          // 16777216
constexpr int HOFF = SOFF + 2 * BB * HH;
constexpr int COFF = HOFF + 2 * BB * HH;

// Workspace layout (float offsets). ~15.3 MB.
constexpr int WS_WC0 = 0;          // [512 j][768 k] vf4  (Wx0;Wh0 stacked)
constexpr int WS_WC1 = 1572864;    // [512 j][1024 k] vf4 (Wx1;Wh1 stacked)
constexpr int WS_BH0 = 3670016;    // [512] vf4
constexpr int WS_BH1 = 3672064;
constexpr int WS_HX0 = 3674112;    // mem exchange: [2 slot][8 g][512 j][8 b] f
constexpr int WS_HX1 = 3739648;    // h1  exchange: same layout

// ---------------- cross-XCD-coherent primitives: DEVICE scope (sc1) ---------
// sc1 = device scope: bypasses the (incoherent) per-XCD L2, MALL-resident.
// r12 lesson: FETCH_SIZE counts TCC<->fabric traffic; MALL hits are behind it.
// ASM NOTE (r16 compile fail): offset: immediate must precede cache flags:
//   "off offset:16 sc1" assembles; "off sc1 offset:16" does NOT.
__device__ __forceinline__ void bypass_st(float* p, float v) {
  asm volatile("global_store_dword %0, %1, off sc1" :: "v"(p), "v"(v) : "memory");
}
// four 16B loads (2 per array via offset:16), ONE wait; "=&v" load-bearing
__device__ __forceinline__ void bypass_ld4x4(const vf4* p0, const vf4* p1,
                                             vf4& m0, vf4& m1, vf4& h0, vf4& h1) {
  asm volatile(
      "global_load_dwordx4 %0, %4, off sc1\n\t"
      "global_load_dwordx4 %1, %4, off offset:16 sc1\n\t"
      "global_load_dwordx4 %2, %5, off sc1\n\t"
      "global_load_dwordx4 %3, %5, off offset:16 sc1\n\t"
      "s_waitcnt vmcnt(0)"
      : "=&v"(m0), "=&v"(m1), "=&v"(h0), "=&v"(h1)
      : "v"(p0), "v"(p1) : "memory");
}

// ---------------- self-validating tagged exchange ----------------
// Values exchanged are bounded: mem in (-1,1), h1 in (-0.2,1.2). Producer at
// step t stores  v' = v + OFF(t),  OFF(t) = 4 + 4*((t>>1)&1)  -> bands
// (3,5.2) for tag0, (7,9.2) for tag1. A slot is revisited at t+2, whose tag
// always FLIPS, and memset zeros match neither band — so band membership ==
// "this step's value is here". The tag travels IN the same atomic dword as
// the data: no flags, no release drain. Decode rounding ~1ulp@8.5 per step;
// observed absmax 0.0083 << 0.0323 threshold (r13-r15).
__device__ __forceinline__ bool tag_ok(float v, bool hi) {
  return hi ? (v > 6.0f) : (v > 2.0f && v < 6.0f);
}
__device__ __forceinline__ bool tag_ok4(vf4 v, bool hi) {
  return tag_ok(v.x, hi) && tag_ok(v.y, hi) && tag_ok(v.z, hi) && tag_ok(v.w, hi);
}

__device__ __forceinline__ float sigf(float x) { return 1.0f / (1.0f + __expf(-x)); }
__device__ __forceinline__ float tanh_fast(float x) {
  return 1.0f - 2.0f / (1.0f + __expf(2.0f * x));
}

__device__ __forceinline__ float sxor(float v, int m) { return __shfl_xor(v, m, 64); }
__device__ __forceinline__ vf4 sxor4(vf4 v, int m) {
  vf4 r; r.x = sxor(v.x, m); r.y = sxor(v.y, m); r.z = sxor(v.z, m); r.w = sxor(v.w, m);
  return r;
}

// 3-bit bit-reversal (self-inverse): lane<->batch map for the split butterfly
__device__ __forceinline__ int rev3(int v) {
  return ((v & 1) << 2) | (v & 2) | ((v >> 2) & 1);
}

// Batch-splitting butterfly: in: acc[8] = partials for batches 0..7 over this
// lane's k-chunk. out: complete wave-sum vf4 for batch rev3(kl&7) (8 replicas).
__device__ __forceinline__ vf4 reduce8(const vf4* acc, int kl) {
  const int sel = kl & 1;
  vf4 n0[4];
#pragma unroll
  for (int i = 0; i < 4; ++i) {
    vf4 snd = sel ? acc[i] : acc[i + 4];
    vf4 kp  = sel ? acc[i + 4] : acc[i];
    n0[i] = kp + sxor4(snd, 1);
  }
  const int sel2 = (kl >> 1) & 1;
  vf4 n1[2];
#pragma unroll
  for (int i = 0; i < 2; ++i) {
    vf4 snd = sel2 ? n0[i] : n0[i + 2];
    vf4 kp  = sel2 ? n0[i + 2] : n0[i];
    n1[i] = kp + sxor4(snd, 2);
  }
  const int sel3 = (kl >> 2) & 1;
  vf4 snd = sel3 ? n1[0] : n1[1];
  vf4 kp  = sel3 ? n1[1] : n1[0];
  vf4 r = kp + sxor4(snd, 4);
  r += sxor4(r, 8);
  r += sxor4(r, 16);
  r += sxor4(r, 32);
  return r;
}

// ---------------- setup kernels ----------------
__global__ void pack_wc(const float* __restrict__ A, const float* __restrict__ B,
                        int Ka, int K, float* __restrict__ Wp) {
  const int j = blockIdx.x;
  for (int k = threadIdx.x; k < K; k += 256) {
    const float* src = (k < Ka) ? (A + (size_t)k * 2048) : (B + (size_t)(k - Ka) * 2048);
    vf4 v = {src[j], src[512 + j], src[1024 + j], src[1536 + j]};
    ((vf4*)Wp)[(size_t)j * K + k] = v;
  }
}

__global__ void pack_bias(const float* __restrict__ bh0, const float* __restrict__ bh1,
                          float* __restrict__ bh0p, float* __restrict__ bh1p) {
  const int i = blockIdx.x * blockDim.x + threadIdx.x;  // 4096
  if (i < 2048) {
    bh0p[i] = bh0[(i & 3) * 512 + (i >> 2)];
  } else {
    int q = i - 2048;
    bh1p[q] = bh1[(q & 3) * 512 + (q >> 2)];
  }
}

// hx1 slot1 must read as "h1(-1)=0 with tag1" at t=0: fill with 0 + 8.0.
__global__ void fill_tag(float* __restrict__ p, float v) {
  p[blockIdx.x * 1024 + threadIdx.x] = v;
}

// ---------------- main persistent kernel ----------------
// Round 17 (= r16 + asm operand-order fix): TWO independent blocks per CU.
//  - 512 blocks x 512 threads (8 waves, 8 j-columns each). LDS single-buffered
//    (57.9 KB) so 2 blocks co-reside per CU: when one block stalls in its
//    poll/barrier/L2 burst, the other's 8 waves compute. r15 evidence: 16-wave
//    single-domain blocks idle 8us/step (VALUBusy 45%, all waves stall
//    together).
//  - Schedule: r11-proven 2-barrier order (dot0 -> store -> S1 -> poll/scatter
//    -> S2 -> dot1 -> store), with the r13 tagged exchange (no flags/drains).
//    Ring safety: mem(t+2) overwrite happens-after all peers read mem(t)
//    [witness: mem(t+1) poll]; h1(t+2) after all peers read h1(t) [witness:
//    h1(t+1) poll; h1(t) is read in staging BEFORE h1(t+1) is produced].
//  - Staging: thread i owns column j=i of the group's [g][j][b] region:
//    2 mem vf4 + 2 h1 vf4 (one wait), scatters 8 batches. Conflict-free LDS.
//  - Escalating poll backoff (>4: sleep(1), >16: sleep(4)).
__global__ __launch_bounds__(512, 4) void aslstm_main(
    const vf4* __restrict__ Wc0p, const vf4* __restrict__ Wc1p,
    const vf4* __restrict__ bh0p, const vf4* __restrict__ bh1p,
    const float* __restrict__ x,
    float* __restrict__ hx0, float* __restrict__ hx1,
    float* __restrict__ out) {
  const int wg  = blockIdx.x;
  const int xcd = wg & 7;
  const int a   = wg >> 3;          // 0..63
  const int g   = a & 7;            // group (8 batches)
  const int s   = (a >> 3) * 8 + xcd;  // producer slot 0..63 (XCD-affine weights)
  const int tid = threadIdx.x;      // 0..511
  const int jo  = tid >> 6;         // wave -> j column (0..7)
  const int kl  = tid & 63;         // lane -> k chunk
  const int j   = s * 8 + jo;       // this wave's output column
  const int b_loc  = rev3(kl & 7);  // batch this lane finalizes (8 replicas)
  const int b_glob = g * 8 + b_loc;
  const bool rep0  = (kl < 8);      // replica 0 does the stores

  __shared__ float cat0[8][776];    // [b][ x(256) | h0(512) | pad ]
  __shared__ float cat1[8][1032];   // [b][ s0(512) | h1(512) | pad ]

  float c0 = 0.0f, c1 = 0.0f, sp = 0.0f;

  // staging: thread i owns column i of the group's [j][b] exchange region
  const int fo = g * 4096 + tid * 8;   // float offset of (j=tid, b=0..7)

  // ---- loop-invariant dot0 weights -> regs (12 vf4; compiler may remat) ----
  vf4 w0r[3][4];
  {
    const vf4* wr = Wc0p + (size_t)j * 768;
#pragma unroll
    for (int ig = 0; ig < 3; ++ig) {
      const int k0 = ig * 256 + kl * 4;
#pragma unroll
      for (int q = 0; q < 4; ++q) w0r[ig][q] = wr[k0 + q];
    }
  }

  // ---- prologue: stage x(0); h0(-1)=0 directly in LDS ----
  {
    int bx = tid >> 6, kx = (tid & 63) * 4;
    *(vf4*)&cat0[bx][kx] = *(const vf4*)&x[(size_t)(g * 8 + bx) * (T * II) + kx];
    int kz = (tid & 63) * 8;
    *(vf4*)&cat0[bx][256 + kz] = vf4{0.0f, 0.0f, 0.0f, 0.0f};
    *(vf4*)&cat0[bx][256 + kz + 4] = vf4{0.0f, 0.0f, 0.0f, 0.0f};
  }
  __syncthreads();

  for (int t = 0; t < T; ++t) {
    const int p0 = t & 1, p1 = p0 ^ 1;
    const bool tagm = ((t >> 1) & 1) != 0;        // band of step-t values
    const bool tagh = (((t + 3) >> 1) & 1) != 0;  // band of step-(t-1) values
    const float offm = tagm ? 8.0f : 4.0f;
    const float offh = tagh ? 8.0f : 4.0f;

    // ---------- dot0: [x_t ; h0[t-1]] @ Wc0 (K=768) ----------
    vf4 acc[8];
#pragma unroll
    for (int b = 0; b < 8; ++b) acc[b] = vf4{0, 0, 0, 0};
#pragma unroll
    for (int ig = 0; ig < 3; ++ig) {
      const int k0 = ig * 256 + kl * 4;
#pragma unroll
      for (int b = 0; b < 8; ++b) {
        vf4 av = *(const vf4*)&cat0[b][k0];
        acc[b] += av.x * w0r[ig][0]; acc[b] += av.y * w0r[ig][1];
        acc[b] += av.z * w0r[ig][2]; acc[b] += av.w * w0r[ig][3];
      }
    }

    // ---------- in-wave reduce + finalize layer 0 (registers only) ----------
    {
      vf4 p = reduce8(acc, kl) + bh0p[j];
      float cn  = sigf(p.y) * c0 + sigf(p.x) * tanh_fast(p.z);
      float mem = sigf(p.w) * tanh_fast(cn);   // s*0.2*(1-s) == 0 for s in {0,1}
      float sn  = (mem > 0.5f) ? 1.0f : 0.0f;
      c0 = cn; sp = sn;
      if (rep0) {
        // tagged store: [g][j][b] layout, 8 lanes -> one 32B packet per wave
        bypass_st(&hx0[p0 * 32768 + g * 4096 + j * 8 + b_loc], mem + offm);
        if (t == T - 1) {
          out[SOFF + b_glob * 512 + j] = sn;
          out[HOFF + b_glob * 512 + j] = mem;
          out[COFF + b_glob * 512 + j] = cn;
        }
      }
    }

    // x(t+1) prefetch into regs (plain cached load)
    vf4 xv = vf4{0, 0, 0, 0};
    if (t < T - 1) {
      int bx = tid >> 6, kx = (tid & 63) * 4;
      xv = *(const vf4*)&x[(size_t)(g * 8 + bx) * (T * II) + (size_t)(t + 1) * II + kx];
    }

    __syncthreads();  // S1 — all waves done reading cat0/cat1 of this step

    // ---------- productive poll (col tid): retry loads until band-valid ----------
    {
      const vf4* mp = (const vf4*)(hx0 + p0 * 32768 + fo);  // mem(t),  b=0..7
      const vf4* hp = (const vf4*)(hx1 + p1 * 32768 + fo);  // h1(t-1), b=0..7
      vf4 m0, m1, h0v, h1v;
      int tries = 0;
      for (;;) {
        bypass_ld4x4(mp, hp, m0, m1, h0v, h1v);
        bool ok = tag_ok4(m0, tagm) && tag_ok4(m1, tagm) &&
                  tag_ok4(h0v, tagh) && tag_ok4(h1v, tagh);
        if (__all(ok)) break;
        ++tries;
        if (tries > 16)     __builtin_amdgcn_s_sleep(4);
        else if (tries > 4) __builtin_amdgcn_s_sleep(1);
      }
      const vf4 om = {offm, offm, offm, offm};
      const vf4 oh = {offh, offh, offh, offh};
      vf4 ma = m0 - om, mb = m1 - om;
      vf4 ha = h0v - oh, hb = h1v - oh;
      const int jc = tid;  // column this thread carries
      // h0 -> cat0 (batches 0..3 from ma, 4..7 from mb)
      cat0[0][256 + jc] = ma.x; cat0[1][256 + jc] = ma.y;
      cat0[2][256 + jc] = ma.z; cat0[3][256 + jc] = ma.w;
      cat0[4][256 + jc] = mb.x; cat0[5][256 + jc] = mb.y;
      cat0[6][256 + jc] = mb.z; cat0[7][256 + jc] = mb.w;
      // spikes -> cat1 first half
      cat1[0][jc] = (ma.x > 0.5f) ? 1.0f : 0.0f;
      cat1[1][jc] = (ma.y > 0.5f) ? 1.0f : 0.0f;
      cat1[2][jc] = (ma.z > 0.5f) ? 1.0f : 0.0f;
      cat1[3][jc] = (ma.w > 0.5f) ? 1.0f : 0.0f;
      cat1[4][jc] = (mb.x > 0.5f) ? 1.0f : 0.0f;
      cat1[5][jc] = (mb.y > 0.5f) ? 1.0f : 0.0f;
      cat1[6][jc] = (mb.z > 0.5f) ? 1.0f : 0.0f;
      cat1[7][jc] = (mb.w > 0.5f) ? 1.0f : 0.0f;
      // h1 -> cat1 second half
      cat1[0][512 + jc] = ha.x; cat1[1][512 + jc] = ha.y;
      cat1[2][512 + jc] = ha.z; cat1[3][512 + jc] = ha.w;
      cat1[4][512 + jc] = hb.x; cat1[5][512 + jc] = hb.y;
      cat1[6][512 + jc] = hb.z; cat1[7][512 + jc] = hb.w;
      // x(t+1)
      {
        int bx = tid >> 6, kx = (tid & 63) * 4;
        *(vf4*)&cat0[bx][kx] = xv;
      }
    }
    __syncthreads();  // S2 — staging visible to all waves

    // ---------- dot1: [s0[t] ; h1[t-1]] @ Wc1 (K=1024), streamed weights ----------
#pragma unroll
    for (int b = 0; b < 8; ++b) acc[b] = vf4{0, 0, 0, 0};
    {
      const vf4* wr = Wc1p + (size_t)j * 1024;
#pragma unroll
      for (int ig = 0; ig < 4; ++ig) {
        const int k0 = ig * 256 + kl * 4;
        vf4 w0 = wr[k0], w1 = wr[k0 + 1], w2 = wr[k0 + 2], w3 = wr[k0 + 3];
#pragma unroll
        for (int b = 0; b < 8; ++b) {
          vf4 av = *(const vf4*)&cat1[b][k0];
          acc[b] += av.x * w0; acc[b] += av.y * w1;
          acc[b] += av.z * w2; acc[b] += av.w * w3;
        }
      }
    }

    // ---------- in-wave reduce + finalize layer 1 (registers only) ----------
    {
      vf4 p = reduce8(acc, kl) + bh1p[j];
      float cn  = sigf(p.y) * c1 + sigf(p.x) * tanh_fast(p.z);
      float hn  = sigf(p.w) * tanh_fast(cn);
      float h1n = hn * 0.2f + sp;              // output neuron: h*decay + input(spike)
      c1 = cn;
      if (rep0) {
        // tagged store; consumers at t+1 expect band tagm(t)
        bypass_st(&hx1[p0 * 32768 + g * 4096 + j * 8 + b_loc], h1n + offm);
        out[(size_t)b_glob * (T * HH) + (size_t)t * HH + j] = h1n;
        if (t == T - 1) {
          out[HOFF + 32768 + b_glob * 512 + j] = h1n;
          out[COFF + 32768 + b_glob * 512 + j] = cn;
        }
      }
    }
    // no trailing barrier: dot0(t+1) reads cat0 written pre-S2(t); the next
    // writes to cat0/cat1 happen only after S1(t+1), past all step-t readers.
  }
}

// ---------------- launch ----------------
extern "C" void kernel_launch(void* const* d_in, const int* in_sizes, int n_in,
                              void* d_out, int out_size, void* d_ws, size_t ws_size,
                              hipStream_t stream) {
  const float* x   = (const float*)d_in[0];
  const float* Wx0 = (const float*)d_in[1];
  const float* Wh0 = (const float*)d_in[2];
  const float* bh0 = (const float*)d_in[3];
  const float* Wx1 = (const float*)d_in[4];
  const float* Wh1 = (const float*)d_in[5];
  const float* bh1 = (const float*)d_in[6];
  float* out = (float*)d_out;
  float* ws  = (float*)d_ws;

  float* Wc0p  = ws + WS_WC0;
  float* Wc1p  = ws + WS_WC1;
  float* bh0pf = ws + WS_BH0;
  float* bh1pf = ws + WS_BH1;
  float* hx0   = ws + WS_HX0;
  float* hx1   = ws + WS_HX1;

  // zero both hx0 slots + hx1 slot0 (zeros = no valid band); fill hx1 slot1
  // with 0 + tag1 offset (8.0f) so t=0 reads h1(-1)=0 as already-valid.
  hipMemsetAsync(hx0, 0, 2 * 64 * 512 * sizeof(float), stream);
  hipMemsetAsync(hx1, 0, 64 * 512 * sizeof(float), stream);
  hipMemsetAsync(out + SOFF + BB * HH, 0, BB * HH * sizeof(float), stream);

  pack_wc<<<dim3(512), dim3(256), 0, stream>>>(Wx0, Wh0, 256, 768, Wc0p);
  pack_wc<<<dim3(512), dim3(256), 0, stream>>>(Wx1, Wh1, 512, 1024, Wc1p);
  pack_bias<<<dim3(16), dim3(256), 0, stream>>>(bh0, bh1, bh0pf, bh1pf);
  fill_tag<<<dim3(32), dim3(1024), 0, stream>>>(hx1 + 32768, 8.0f);

  aslstm_main<<<dim3(512), dim3(512), 0, stream>>>(
      (const vf4*)Wc0p, (const vf4*)Wc1p, (const vf4*)bh0pf, (const vf4*)bh1pf,
      x, hx0, hx1, out);
}

// Round 11
// 7692.811 us; speedup vs baseline: 1.0699x; 1.0699x over previous
//
#include <hip/hip_runtime.h>
#include <math.h>

typedef float vf4 __attribute__((ext_vector_type(4)));

// Problem dims (fixed by reference)
constexpr int T  = 512;
constexpr int BB = 64;    // batch
constexpr int II = 256;   // input
constexpr int HH = 512;   // hidden

// d_out layout (floats): out[B,T,H] | s[2,B,H] | h[2,B,H] | c[2,B,H]
constexpr int SOFF = BB * T * HH;          // 16777216
constexpr int HOFF = SOFF + 2 * BB * HH;
constexpr int COFF = HOFF + 2 * BB * HH;

// Workspace layout (float offsets). ~15.3 MB.
constexpr int WS_WC0 = 0;          // [512 j][768 k] vf4  (Wx0;Wh0 stacked)
constexpr int WS_WC1 = 1572864;    // [512 j][1024 k] vf4 (Wx1;Wh1 stacked)
constexpr int WS_BH0 = 3670016;    // [512] vf4
constexpr int WS_BH1 = 3672064;
constexpr int WS_HX0 = 3674112;    // mem exchange: [2 slot][8 g][512 j][8 b] f
constexpr int WS_HX1 = 3739648;    // h1  exchange: same layout

// ---------------- cross-XCD-coherent primitives: DEVICE scope (sc1) ---------
// sc1 = device scope: bypasses the (incoherent) per-XCD L2, MALL-resident.
// r12 lesson: FETCH_SIZE counts TCC<->fabric traffic; MALL hits are behind it.
__device__ __forceinline__ void bypass_st(float* p, float v) {
  asm volatile("global_store_dword %0, %1, off sc1" :: "v"(p), "v"(v) : "memory");
}
// two 16B loads, ONE wait (batched latency); "=&v" early-clobber load-bearing
__device__ __forceinline__ void bypass_ld2x4(const vf4* p0, const vf4* p1, vf4& r0, vf4& r1) {
  asm volatile(
      "global_load_dwordx4 %0, %2, off sc1\n\t"
      "global_load_dwordx4 %1, %3, off sc1\n\t"
      "s_waitcnt vmcnt(0)"
      : "=&v"(r0), "=&v"(r1) : "v"(p0), "v"(p1) : "memory");
}

// ---------------- self-validating tagged exchange ----------------
// Values exchanged are bounded: mem in (-1,1), h1 in (-0.2,1.2). Producer at
// step t stores  v' = v + OFF(t),  OFF(t) = 4 + 4*((t>>1)&1)  -> bands
// (3,5.2) for tag0, (7,9.2) for tag1. A slot is revisited at t+2, whose tag
// always FLIPS, and memset zeros match neither band — so band membership ==
// "this step's value is here". The tag travels IN the same atomic dword as
// the data: no flags, no release drain. Decode rounding ~1ulp@8.5 per step;
// observed absmax 0.0083 << 0.0323 threshold (r13-r15).
__device__ __forceinline__ bool tag_ok(float v, bool hi) {
  return hi ? (v > 6.0f) : (v > 2.0f && v < 6.0f);
}

__device__ __forceinline__ float sigf(float x) { return 1.0f / (1.0f + __expf(-x)); }
__device__ __forceinline__ float tanh_fast(float x) {
  return 1.0f - 2.0f / (1.0f + __expf(2.0f * x));
}

__device__ __forceinline__ float sxor(float v, int m) { return __shfl_xor(v, m, 64); }
__device__ __forceinline__ vf4 sxor4(vf4 v, int m) {
  vf4 r; r.x = sxor(v.x, m); r.y = sxor(v.y, m); r.z = sxor(v.z, m); r.w = sxor(v.w, m);
  return r;
}

// 3-bit bit-reversal (self-inverse): lane<->batch map for the split butterfly
__device__ __forceinline__ int rev3(int v) {
  return ((v & 1) << 2) | (v & 2) | ((v >> 2) & 1);
}

// Batch-splitting butterfly: in: acc[8] = partials for batches 0..7 over this
// lane's k-chunk. out: complete wave-sum vf4 for batch rev3(kl&7) (8 replicas).
__device__ __forceinline__ vf4 reduce8(const vf4* acc, int kl) {
  const int sel = kl & 1;
  vf4 n0[4];
#pragma unroll
  for (int i = 0; i < 4; ++i) {
    vf4 snd = sel ? acc[i] : acc[i + 4];
    vf4 kp  = sel ? acc[i + 4] : acc[i];
    n0[i] = kp + sxor4(snd, 1);
  }
  const int sel2 = (kl >> 1) & 1;
  vf4 n1[2];
#pragma unroll
  for (int i = 0; i < 2; ++i) {
    vf4 snd = sel2 ? n0[i] : n0[i + 2];
    vf4 kp  = sel2 ? n0[i + 2] : n0[i];
    n1[i] = kp + sxor4(snd, 2);
  }
  const int sel3 = (kl >> 2) & 1;
  vf4 snd = sel3 ? n1[0] : n1[1];
  vf4 kp  = sel3 ? n1[1] : n1[0];
  vf4 r = kp + sxor4(snd, 4);
  r += sxor4(r, 8);
  r += sxor4(r, 16);
  r += sxor4(r, 32);
  return r;
}

// ---------------- setup kernels ----------------
__global__ void pack_wc(const float* __restrict__ A, const float* __restrict__ B,
                        int Ka, int K, float* __restrict__ Wp) {
  const int j = blockIdx.x;
  for (int k = threadIdx.x; k < K; k += 256) {
    const float* src = (k < Ka) ? (A + (size_t)k * 2048) : (B + (size_t)(k - Ka) * 2048);
    vf4 v = {src[j], src[512 + j], src[1024 + j], src[1536 + j]};
    ((vf4*)Wp)[(size_t)j * K + k] = v;
  }
}

__global__ void pack_bias(const float* __restrict__ bh0, const float* __restrict__ bh1,
                          float* __restrict__ bh0p, float* __restrict__ bh1p) {
  const int i = blockIdx.x * blockDim.x + threadIdx.x;  // 4096
  if (i < 2048) {
    bh0p[i] = bh0[(i & 3) * 512 + (i >> 2)];
  } else {
    int q = i - 2048;
    bh1p[q] = bh1[(q & 3) * 512 + (q >> 2)];
  }
}

// hx1 slot1 must read as "h1(-1)=0 with tag1" at t=0: fill with 0 + 8.0.
__global__ void fill_tag(float* __restrict__ p, float v) {
  p[blockIdx.x * 1024 + threadIdx.x] = v;
}

// ---------------- main persistent kernel ----------------
// Round 18 (= r14 champion, 7460us, + deferred coalesced out-writes).
//  - r17 lesson: 2 blocks/CU regressed (doubled exchange traffic + 64-producer
//    straggler tail). Reverted to 256 blocks x 1024 threads, 1 block/CU.
//  - NEW: out[b][t][j] is NOT written scattered in finalize1 (was 128 dwords
//    1MB apart per block-step -> ~2MB/step write-allocate traffic, whose acks
//    sat in the next poll's vmcnt(0) window). Instead, h1(t-1) — already
//    staged in cat1[p0][b][512+j] by scatter(t) — is written after S2(t) as
//    8 rows x 2KB coalesced vf4 stores (1 per thread). Scattered path remains
//    only for row T-1 (never passes through staging).
//    Safety: cat1[p0] stable from S2(t) until scatter(t+2) (fenced by
//    S2(t+1)); stores drain during dot1+dot0 (~4us) before the next poll.
//  - Tagged exchange, ONE barrier per step (r13); escalating poll backoff.
__global__ __launch_bounds__(1024, 1) void aslstm_main(
    const vf4* __restrict__ Wc0p, const vf4* __restrict__ Wc1p,
    const vf4* __restrict__ bh0p, const vf4* __restrict__ bh1p,
    const float* __restrict__ x,
    float* __restrict__ hx0, float* __restrict__ hx1,
    float* __restrict__ out) {
  const int wg  = blockIdx.x;
  const int xcd = wg & 7;
  const int a   = wg >> 3;
  const int g   = a & 7;
  const int s   = (a >> 3) * 8 + xcd;
  const int tid = threadIdx.x;
  const int jo  = tid >> 6;          // wave -> j column
  const int kl  = tid & 63;          // lane -> k chunk
  const int j   = s * 16 + jo;
  const int b_loc  = rev3(kl & 7);   // batch this lane finalizes (8 replicas)
  const int b_glob = g * 8 + b_loc;
  const bool rep0  = (kl < 8);       // replica 0 does the stores

  __shared__ float cat0[2][8][776];   // [buf][b][ x(256) | h0(512) | pad ]
  __shared__ float cat1[2][8][1032];  // [buf][b][ s0(512) | h1(512) | pad ]

  float c0 = 0.0f, c1 = 0.0f, sp = 0.0f;

  // producer this wave waits on + its load chunk within that producer's region
  const int pl = (jo << 1) | (kl >> 5);   // producer block 0..31 (per lane half)
  const int lc = kl & 31;                 // vf4 chunk 0..31 within producer
  const int js = pl * 16 + (lc >> 1);     // column this chunk carries
  const int b0 = (lc & 1) * 4;            // first batch of the chunk
  const int fo = g * 4096 + pl * 128 + lc * 4;  // float offset in hx[slot]

  // out-write assignment: thread -> (batch row, col quad) for coalesced rows
  const int ob = tid >> 7;                // batch 0..7
  const int oc = (tid & 127) * 4;         // col 0..508
  float* const orow_base = out + (size_t)(g * 8 + ob) * (T * HH) + oc;

  // ---- loop-invariant dot0 weights -> regs (12 vf4; compiler may remat) ----
  vf4 w0r[3][4];
  {
    const vf4* wr = Wc0p + (size_t)j * 768;
#pragma unroll
    for (int ig = 0; ig < 3; ++ig) {
      const int k0 = ig * 256 + kl * 4;
#pragma unroll
      for (int q = 0; q < 4; ++q) w0r[ig][q] = wr[k0 + q];
    }
  }

  // ---- prologue: stage x(0); h0(-1)=0 directly in LDS buf0 ----
  if (tid < 512) {
    int bx = tid >> 6, kx = (tid & 63) * 4;
    *(vf4*)&cat0[0][bx][kx] = *(const vf4*)&x[(size_t)(g * 8 + bx) * (T * II) + kx];
  }
  {
    int bz = tid >> 7, kz = (tid & 127) * 4;
    *(vf4*)&cat0[0][bz][256 + kz] = vf4{0.0f, 0.0f, 0.0f, 0.0f};
  }
  __syncthreads();

  for (int t = 0; t < T; ++t) {
    const int p0 = t & 1, p1 = p0 ^ 1;
    const bool tagm = ((t >> 1) & 1) != 0;        // band of step-t values
    const bool tagh = (((t + 3) >> 1) & 1) != 0;  // band of step-(t-1) values
    const float offm = tagm ? 8.0f : 4.0f;
    const float offh = tagh ? 8.0f : 4.0f;

    // ---------- dot0: [x_t ; h0[t-1]] @ Wc0 (K=768) ----------
    vf4 acc[8];
#pragma unroll
    for (int b = 0; b < 8; ++b) acc[b] = vf4{0, 0, 0, 0};
#pragma unroll
    for (int ig = 0; ig < 3; ++ig) {
      const int k0 = ig * 256 + kl * 4;
#pragma unroll
      for (int b = 0; b < 8; ++b) {
        vf4 av = *(const vf4*)&cat0[p0][b][k0];
        acc[b] += av.x * w0r[ig][0]; acc[b] += av.y * w0r[ig][1];
        acc[b] += av.z * w0r[ig][2]; acc[b] += av.w * w0r[ig][3];
      }
    }

    // ---------- in-wave reduce + finalize layer 0 (registers only) ----------
    {
      vf4 p = reduce8(acc, kl) + bh0p[j];
      float cn  = sigf(p.y) * c0 + sigf(p.x) * tanh_fast(p.z);
      float mem = sigf(p.w) * tanh_fast(cn);   // s*0.2*(1-s) == 0 for s in {0,1}
      float sn  = (mem > 0.5f) ? 1.0f : 0.0f;
      c0 = cn; sp = sn;
      if (rep0) {
        // tagged store: value + band offset, one coalesced 32B packet per wave
        bypass_st(&hx0[p0 * 32768 + g * 4096 + j * 8 + b_loc], mem + offm);
        if (t == T - 1) {
          out[SOFF + b_glob * 512 + j] = sn;
          out[HOFF + b_glob * 512 + j] = mem;
          out[COFF + b_glob * 512 + j] = cn;
        }
      }
    }

    // x(t+1) prefetch into regs (plain cached load)
    vf4 xv = vf4{0, 0, 0, 0};
    if (tid < 512 && t < T - 1) {
      int bx = tid >> 6, kx = (tid & 63) * 4;
      xv = *(const vf4*)&x[(size_t)(g * 8 + bx) * (T * II) + (size_t)(t + 1) * II + kx];
    }

    // ---------- productive poll: retry data load until band-valid ----------
    {
      const vf4* mp = (const vf4*)(hx0 + p0 * 32768 + fo);  // mem(t)
      const vf4* hp = (const vf4*)(hx1 + p1 * 32768 + fo);  // h1(t-1)
      vf4 mv, hv;
      int tries = 0;
      for (;;) {
        bypass_ld2x4(mp, hp, mv, hv);
        bool ok = tag_ok(mv.x, tagm) && tag_ok(mv.y, tagm) &&
                  tag_ok(mv.z, tagm) && tag_ok(mv.w, tagm) &&
                  tag_ok(hv.x, tagh) && tag_ok(hv.y, tagh) &&
                  tag_ok(hv.z, tagh) && tag_ok(hv.w, tagh);
        if (__all(ok)) break;
        ++tries;
        if (tries > 16)     __builtin_amdgcn_s_sleep(4);
        else if (tries > 4) __builtin_amdgcn_s_sleep(1);
      }
      const vf4 om = {offm, offm, offm, offm};
      const vf4 oh = {offh, offh, offh, offh};
      vf4 mm = mv - om;
      vf4 hh = hv - oh;
      // scatter to LDS (2-way bank aliasing only — free)
      cat0[p1][b0 + 0][256 + js] = mm.x;
      cat0[p1][b0 + 1][256 + js] = mm.y;
      cat0[p1][b0 + 2][256 + js] = mm.z;
      cat0[p1][b0 + 3][256 + js] = mm.w;
      cat1[p0][b0 + 0][js] = (mm.x > 0.5f) ? 1.0f : 0.0f;   // spike recompute
      cat1[p0][b0 + 1][js] = (mm.y > 0.5f) ? 1.0f : 0.0f;
      cat1[p0][b0 + 2][js] = (mm.z > 0.5f) ? 1.0f : 0.0f;
      cat1[p0][b0 + 3][js] = (mm.w > 0.5f) ? 1.0f : 0.0f;
      cat1[p0][b0 + 0][512 + js] = hh.x;
      cat1[p0][b0 + 1][512 + js] = hh.y;
      cat1[p0][b0 + 2][512 + js] = hh.z;
      cat1[p0][b0 + 3][512 + js] = hh.w;
      if (tid < 512) {
        int bx = tid >> 6, kx = (tid & 63) * 4;
        *(vf4*)&cat0[p1][bx][kx] = xv;
      }
    }
    __syncthreads();  // S2 — the ONLY barrier per step

    // ---------- deferred coalesced out-write: row t-1 from staged h1 ----------
    // cat1[p0][b][512+j] == h1(t-1)[b][j]; 1024 threads write 8 rows x 2KB.
    // Fire-and-forget: drains during dot1+dot0 before the next poll.
    if (t > 0) {
      vf4 hrow = *(const vf4*)&cat1[p0][ob][512 + oc];
      *(vf4*)&orow_base[(size_t)(t - 1) * HH] = hrow;
    }

    // ---------- dot1: [s0[t] ; h1[t-1]] @ Wc1 (K=1024), streamed weights ----------
#pragma unroll
    for (int b = 0; b < 8; ++b) acc[b] = vf4{0, 0, 0, 0};
    {
      const vf4* wr = Wc1p + (size_t)j * 1024;
#pragma unroll
      for (int ig = 0; ig < 4; ++ig) {
        const int k0 = ig * 256 + kl * 4;
        vf4 w0 = wr[k0], w1 = wr[k0 + 1], w2 = wr[k0 + 2], w3 = wr[k0 + 3];
#pragma unroll
        for (int b = 0; b < 8; ++b) {
          vf4 av = *(const vf4*)&cat1[p0][b][k0];
          acc[b] += av.x * w0; acc[b] += av.y * w1;
          acc[b] += av.z * w2; acc[b] += av.w * w3;
        }
      }
    }

    // ---------- in-wave reduce + finalize layer 1 (registers only) ----------
    {
      vf4 p = reduce8(acc, kl) + bh1p[j];
      float cn  = sigf(p.y) * c1 + sigf(p.x) * tanh_fast(p.z);
      float hn  = sigf(p.w) * tanh_fast(cn);
      float h1n = hn * 0.2f + sp;              // output neuron: h*decay + input(spike)
      c1 = cn;
      if (rep0) {
        // tagged store; consumers at t+1 expect band tagm(t)
        bypass_st(&hx1[p0 * 32768 + g * 4096 + j * 8 + b_loc], h1n + offm);
        if (t == T - 1) {
          // row T-1 never passes through staging: write it directly (once)
          out[(size_t)b_glob * (T * HH) + (size_t)t * HH + j] = h1n;
          out[HOFF + 32768 + b_glob * 512 + j] = h1n;
          out[COFF + 32768 + b_glob * 512 + j] = cn;
        }
      }
    }
    // no trailing barrier: next dot0 reads cat0[p1] (fully written pre-S2);
    // any wave's step-t+1 scatter targets cat0[p0]/cat1[p1] — disjoint from
    // all step-t readers. One-barrier loop cannot accumulate iteration skew.
  }
}

// ---------------- launch ----------------
extern "C" void kernel_launch(void* const* d_in, const int* in_sizes, int n_in,
                              void* d_out, int out_size, void* d_ws, size_t ws_size,
                              hipStream_t stream) {
  const float* x   = (const float*)d_in[0];
  const float* Wx0 = (const float*)d_in[1];
  const float* Wh0 = (const float*)d_in[2];
  const float* bh0 = (const float*)d_in[3];
  const float* Wx1 = (const float*)d_in[4];
  const float* Wh1 = (const float*)d_in[5];
  const float* bh1 = (const float*)d_in[6];
  float* out = (float*)d_out;
  float* ws  = (float*)d_ws;

  float* Wc0p  = ws + WS_WC0;
  float* Wc1p  = ws + WS_WC1;
  float* bh0pf = ws + WS_BH0;
  float* bh1pf = ws + WS_BH1;
  float* hx0   = ws + WS_HX0;
  float* hx1   = ws + WS_HX1;

  // zero both hx0 slots + hx1 slot0 (zeros = no valid band); fill hx1 slot1
  // with 0 + tag1 offset (8.0f) so t=0 reads h1(-1)=0 as already-valid.
  hipMemsetAsync(hx0, 0, 2 * 64 * 512 * sizeof(float), stream);
  hipMemsetAsync(hx1, 0, 64 * 512 * sizeof(float), stream);
  hipMemsetAsync(out + SOFF + BB * HH, 0, BB * HH * sizeof(float), stream);

  pack_wc<<<dim3(512), dim3(256), 0, stream>>>(Wx0, Wh0, 256, 768, Wc0p);
  pack_wc<<<dim3(512), dim3(256), 0, stream>>>(Wx1, Wh1, 512, 1024, Wc1p);
  pack_bias<<<dim3(16), dim3(256), 0, stream>>>(bh0, bh1, bh0pf, bh1pf);
  fill_tag<<<dim3(32), dim3(1024), 0, stream>>>(hx1 + 32768, 8.0f);

  aslstm_main<<<dim3(256), dim3(1024), 0, stream>>>(
      (const vf4*)Wc0p, (const vf4*)Wc1p, (const vf4*)bh0pf, (const vf4*)bh1pf,
      x, hx0, hx1, out);
}

// Round 12
// 7284.795 us; speedup vs baseline: 1.1298x; 1.0560x over previous
//
#include <hip/hip_runtime.h>
#include <math.h>

typedef float vf4 __attribute__((ext_vector_type(4)));

// Problem dims (fixed by reference)
constexpr int T  = 512;
constexpr int BB = 64;    // batch
constexpr int II = 256;   // input
constexpr int HH = 512;   // hidden

// d_out layout (floats): out[B,T,H] | s[2,B,H] | h[2,B,H] | c[2,B,H]
constexpr int SOFF = BB * T * HH;          // 16777216
constexpr int HOFF = SOFF + 2 * BB * HH;
constexpr int COFF = HOFF + 2 * BB * HH;

// Workspace layout (float offsets). ~15.3 MB.
constexpr int WS_WC0 = 0;          // [512 j][768 k] vf4  (Wx0;Wh0 stacked)
constexpr int WS_WC1 = 1572864;    // [512 j][1024 k] vf4 (Wx1;Wh1 stacked)
constexpr int WS_BH0 = 3670016;    // [512] vf4
constexpr int WS_BH1 = 3672064;
constexpr int WS_HX0 = 3674112;    // mem exchange: [2 slot][8 g][512 j][8 b] f
constexpr int WS_HX1 = 3739648;    // h1  exchange: same layout

// ---------------- cross-XCD-coherent primitives: DEVICE scope (sc1) ---------
// sc1 = device scope: bypasses the (incoherent) per-XCD L2, MALL-resident.
// r12 lesson: FETCH_SIZE counts TCC<->fabric traffic; MALL hits are behind it.
__device__ __forceinline__ void bypass_st(float* p, float v) {
  asm volatile("global_store_dword %0, %1, off sc1" :: "v"(p), "v"(v) : "memory");
}
// two 16B loads, ONE wait (batched latency); "=&v" early-clobber load-bearing
__device__ __forceinline__ void bypass_ld2x4(const vf4* p0, const vf4* p1, vf4& r0, vf4& r1) {
  asm volatile(
      "global_load_dwordx4 %0, %2, off sc1\n\t"
      "global_load_dwordx4 %1, %3, off sc1\n\t"
      "s_waitcnt vmcnt(0)"
      : "=&v"(r0), "=&v"(r1) : "v"(p0), "v"(p1) : "memory");
}

// ---------------- self-validating tagged exchange ----------------
// Values exchanged are bounded: mem in (-1,1), h1 in (-0.2,1.2). Producer at
// step t stores  v' = v + OFF(t),  OFF(t) = 4 + 4*((t>>1)&1)  -> bands
// (3,5.2) for tag0, (7,9.2) for tag1. A slot is revisited at t+2, whose tag
// always FLIPS, and memset zeros match neither band — so band membership ==
// "this step's value is here". The tag travels IN the same atomic dword as
// the data: no flags, no release drain. Decode rounding ~1ulp@8.5 per step;
// observed absmax 0.0083 << 0.0323 threshold (r13-r18).
__device__ __forceinline__ bool tag_ok(float v, bool hi) {
  return hi ? (v > 6.0f) : (v > 2.0f && v < 6.0f);
}

__device__ __forceinline__ float sigf(float x) { return 1.0f / (1.0f + __expf(-x)); }
__device__ __forceinline__ float tanh_fast(float x) {
  return 1.0f - 2.0f / (1.0f + __expf(2.0f * x));
}

__device__ __forceinline__ float sxor(float v, int m) { return __shfl_xor(v, m, 64); }
__device__ __forceinline__ vf4 sxor4(vf4 v, int m) {
  vf4 r; r.x = sxor(v.x, m); r.y = sxor(v.y, m); r.z = sxor(v.z, m); r.w = sxor(v.w, m);
  return r;
}

// 3-bit bit-reversal (self-inverse): lane<->batch map for the split butterfly
__device__ __forceinline__ int rev3(int v) {
  return ((v & 1) << 2) | (v & 2) | ((v >> 2) & 1);
}

// Batch-splitting butterfly: in: acc[8] = partials for batches 0..7 over this
// lane's k-chunk. out: complete wave-sum vf4 for batch rev3(kl&7) (8 replicas).
__device__ __forceinline__ vf4 reduce8(const vf4* acc, int kl) {
  const int sel = kl & 1;
  vf4 n0[4];
#pragma unroll
  for (int i = 0; i < 4; ++i) {
    vf4 snd = sel ? acc[i] : acc[i + 4];
    vf4 kp  = sel ? acc[i + 4] : acc[i];
    n0[i] = kp + sxor4(snd, 1);
  }
  const int sel2 = (kl >> 1) & 1;
  vf4 n1[2];
#pragma unroll
  for (int i = 0; i < 2; ++i) {
    vf4 snd = sel2 ? n0[i] : n0[i + 2];
    vf4 kp  = sel2 ? n0[i + 2] : n0[i];
    n1[i] = kp + sxor4(snd, 2);
  }
  const int sel3 = (kl >> 2) & 1;
  vf4 snd = sel3 ? n1[0] : n1[1];
  vf4 kp  = sel3 ? n1[1] : n1[0];
  vf4 r = kp + sxor4(snd, 4);
  r += sxor4(r, 8);
  r += sxor4(r, 16);
  r += sxor4(r, 32);
  return r;
}

// ---------------- setup kernels ----------------
__global__ void pack_wc(const float* __restrict__ A, const float* __restrict__ B,
                        int Ka, int K, float* __restrict__ Wp) {
  const int j = blockIdx.x;
  for (int k = threadIdx.x; k < K; k += 256) {
    const float* src = (k < Ka) ? (A + (size_t)k * 2048) : (B + (size_t)(k - Ka) * 2048);
    vf4 v = {src[j], src[512 + j], src[1024 + j], src[1536 + j]};
    ((vf4*)Wp)[(size_t)j * K + k] = v;
  }
}

__global__ void pack_bias(const float* __restrict__ bh0, const float* __restrict__ bh1,
                          float* __restrict__ bh0p, float* __restrict__ bh1p) {
  const int i = blockIdx.x * blockDim.x + threadIdx.x;  // 4096
  if (i < 2048) {
    bh0p[i] = bh0[(i & 3) * 512 + (i >> 2)];
  } else {
    int q = i - 2048;
    bh1p[q] = bh1[(q & 3) * 512 + (q >> 2)];
  }
}

// hx1 slot1 must read as "h1(-1)=0 with tag1" at t=0: fill with 0 + 8.0.
__global__ void fill_tag(float* __restrict__ p, float v) {
  p[blockIdx.x * 1024 + threadIdx.x] = v;
}

// ---------------- main persistent kernel ----------------
// Round 19 (= r14 champion + OWN-COLUMN deferred coalesced out-writes).
//  - r18 lesson: deferring the out-write via staged cat1 was right, but each
//    block wrote ALL 512 columns -> 32x duplication, 4MB/step redundant
//    writes, L2 thrash evicting weights (FETCH +2.7GB). Fix: each block
//    writes row t-1 only for its OWN 16 columns (tid<32: b=tid>>2, one vf4
//    at col s*16+(tid&3)*4), read from cat1[p0][b][512+j]. 8 full 64B lines
//    per block-step vs r14's 128 scattered dwords on 128 lines.
//  - Row T-1 never passes staging: direct scattered store at t==T-1 (once).
//  - Safety: cat1[p0] stable from S2(t) until scatter(t+2) (fenced S2(t+1));
//    stores drain during dot1+dot0 before the next poll's vmcnt(0).
//  - Tagged exchange, ONE barrier per step (r13); escalating poll backoff.
__global__ __launch_bounds__(1024, 1) void aslstm_main(
    const vf4* __restrict__ Wc0p, const vf4* __restrict__ Wc1p,
    const vf4* __restrict__ bh0p, const vf4* __restrict__ bh1p,
    const float* __restrict__ x,
    float* __restrict__ hx0, float* __restrict__ hx1,
    float* __restrict__ out) {
  const int wg  = blockIdx.x;
  const int xcd = wg & 7;
  const int a   = wg >> 3;
  const int g   = a & 7;
  const int s   = (a >> 3) * 8 + xcd;
  const int tid = threadIdx.x;
  const int jo  = tid >> 6;          // wave -> j column
  const int kl  = tid & 63;          // lane -> k chunk
  const int j   = s * 16 + jo;
  const int b_loc  = rev3(kl & 7);   // batch this lane finalizes (8 replicas)
  const int b_glob = g * 8 + b_loc;
  const bool rep0  = (kl < 8);       // replica 0 does the stores

  __shared__ float cat0[2][8][776];   // [buf][b][ x(256) | h0(512) | pad ]
  __shared__ float cat1[2][8][1032];  // [buf][b][ s0(512) | h1(512) | pad ]

  float c0 = 0.0f, c1 = 0.0f, sp = 0.0f;

  // producer this wave waits on + its load chunk within that producer's region
  const int pl = (jo << 1) | (kl >> 5);   // producer block 0..31 (per lane half)
  const int lc = kl & 31;                 // vf4 chunk 0..31 within producer
  const int js = pl * 16 + (lc >> 1);     // column this chunk carries
  const int b0 = (lc & 1) * 4;            // first batch of the chunk
  const int fo = g * 4096 + pl * 128 + lc * 4;  // float offset in hx[slot]

  // own-column out-write: tid<32 -> (batch tid>>2, col quad s*16+(tid&3)*4)
  const int ow_b = tid >> 2;              // 0..7 (valid for tid<32)
  const int ow_c = s * 16 + (tid & 3) * 4;
  float* const ow_base = out + (size_t)(g * 8 + ow_b) * (T * HH) + ow_c;

  // ---- loop-invariant dot0 weights -> regs (12 vf4; compiler may remat) ----
  vf4 w0r[3][4];
  {
    const vf4* wr = Wc0p + (size_t)j * 768;
#pragma unroll
    for (int ig = 0; ig < 3; ++ig) {
      const int k0 = ig * 256 + kl * 4;
#pragma unroll
      for (int q = 0; q < 4; ++q) w0r[ig][q] = wr[k0 + q];
    }
  }

  // ---- prologue: stage x(0); h0(-1)=0 directly in LDS buf0 ----
  if (tid < 512) {
    int bx = tid >> 6, kx = (tid & 63) * 4;
    *(vf4*)&cat0[0][bx][kx] = *(const vf4*)&x[(size_t)(g * 8 + bx) * (T * II) + kx];
  }
  {
    int bz = tid >> 7, kz = (tid & 127) * 4;
    *(vf4*)&cat0[0][bz][256 + kz] = vf4{0.0f, 0.0f, 0.0f, 0.0f};
  }
  __syncthreads();

  for (int t = 0; t < T; ++t) {
    const int p0 = t & 1, p1 = p0 ^ 1;
    const bool tagm = ((t >> 1) & 1) != 0;        // band of step-t values
    const bool tagh = (((t + 3) >> 1) & 1) != 0;  // band of step-(t-1) values
    const float offm = tagm ? 8.0f : 4.0f;
    const float offh = tagh ? 8.0f : 4.0f;

    // ---------- dot0: [x_t ; h0[t-1]] @ Wc0 (K=768) ----------
    vf4 acc[8];
#pragma unroll
    for (int b = 0; b < 8; ++b) acc[b] = vf4{0, 0, 0, 0};
#pragma unroll
    for (int ig = 0; ig < 3; ++ig) {
      const int k0 = ig * 256 + kl * 4;
#pragma unroll
      for (int b = 0; b < 8; ++b) {
        vf4 av = *(const vf4*)&cat0[p0][b][k0];
        acc[b] += av.x * w0r[ig][0]; acc[b] += av.y * w0r[ig][1];
        acc[b] += av.z * w0r[ig][2]; acc[b] += av.w * w0r[ig][3];
      }
    }

    // ---------- in-wave reduce + finalize layer 0 (registers only) ----------
    {
      vf4 p = reduce8(acc, kl) + bh0p[j];
      float cn  = sigf(p.y) * c0 + sigf(p.x) * tanh_fast(p.z);
      float mem = sigf(p.w) * tanh_fast(cn);   // s*0.2*(1-s) == 0 for s in {0,1}
      float sn  = (mem > 0.5f) ? 1.0f : 0.0f;
      c0 = cn; sp = sn;
      if (rep0) {
        // tagged store: value + band offset, one coalesced 32B packet per wave
        bypass_st(&hx0[p0 * 32768 + g * 4096 + j * 8 + b_loc], mem + offm);
        if (t == T - 1) {
          out[SOFF + b_glob * 512 + j] = sn;
          out[HOFF + b_glob * 512 + j] = mem;
          out[COFF + b_glob * 512 + j] = cn;
        }
      }
    }

    // x(t+1) prefetch into regs (plain cached load)
    vf4 xv = vf4{0, 0, 0, 0};
    if (tid < 512 && t < T - 1) {
      int bx = tid >> 6, kx = (tid & 63) * 4;
      xv = *(const vf4*)&x[(size_t)(g * 8 + bx) * (T * II) + (size_t)(t + 1) * II + kx];
    }

    // ---------- productive poll: retry data load until band-valid ----------
    {
      const vf4* mp = (const vf4*)(hx0 + p0 * 32768 + fo);  // mem(t)
      const vf4* hp = (const vf4*)(hx1 + p1 * 32768 + fo);  // h1(t-1)
      vf4 mv, hv;
      int tries = 0;
      for (;;) {
        bypass_ld2x4(mp, hp, mv, hv);
        bool ok = tag_ok(mv.x, tagm) && tag_ok(mv.y, tagm) &&
                  tag_ok(mv.z, tagm) && tag_ok(mv.w, tagm) &&
                  tag_ok(hv.x, tagh) && tag_ok(hv.y, tagh) &&
                  tag_ok(hv.z, tagh) && tag_ok(hv.w, tagh);
        if (__all(ok)) break;
        ++tries;
        if (tries > 16)     __builtin_amdgcn_s_sleep(4);
        else if (tries > 4) __builtin_amdgcn_s_sleep(1);
      }
      const vf4 om = {offm, offm, offm, offm};
      const vf4 oh = {offh, offh, offh, offh};
      vf4 mm = mv - om;
      vf4 hh = hv - oh;
      // scatter to LDS (2-way bank aliasing only — free)
      cat0[p1][b0 + 0][256 + js] = mm.x;
      cat0[p1][b0 + 1][256 + js] = mm.y;
      cat0[p1][b0 + 2][256 + js] = mm.z;
      cat0[p1][b0 + 3][256 + js] = mm.w;
      cat1[p0][b0 + 0][js] = (mm.x > 0.5f) ? 1.0f : 0.0f;   // spike recompute
      cat1[p0][b0 + 1][js] = (mm.y > 0.5f) ? 1.0f : 0.0f;
      cat1[p0][b0 + 2][js] = (mm.z > 0.5f) ? 1.0f : 0.0f;
      cat1[p0][b0 + 3][js] = (mm.w > 0.5f) ? 1.0f : 0.0f;
      cat1[p0][b0 + 0][512 + js] = hh.x;
      cat1[p0][b0 + 1][512 + js] = hh.y;
      cat1[p0][b0 + 2][512 + js] = hh.z;
      cat1[p0][b0 + 3][512 + js] = hh.w;
      if (tid < 512) {
        int bx = tid >> 6, kx = (tid & 63) * 4;
        *(vf4*)&cat0[p1][bx][kx] = xv;
      }
    }
    __syncthreads();  // S2 — the ONLY barrier per step

    // ---------- deferred coalesced out-write: row t-1, OWN columns only ----------
    // cat1[p0][b][512+j] == h1(t-1)[b][j]; 32 threads x 1 vf4 = 8 full 64B
    // lines per block-step (vs 128 scattered dwords in r14). Fire-and-forget.
    if (t > 0 && tid < 32) {
      vf4 hrow = *(const vf4*)&cat1[p0][ow_b][512 + ow_c];
      *(vf4*)&ow_base[(size_t)(t - 1) * HH] = hrow;
    }

    // ---------- dot1: [s0[t] ; h1[t-1]] @ Wc1 (K=1024), streamed weights ----------
#pragma unroll
    for (int b = 0; b < 8; ++b) acc[b] = vf4{0, 0, 0, 0};
    {
      const vf4* wr = Wc1p + (size_t)j * 1024;
#pragma unroll
      for (int ig = 0; ig < 4; ++ig) {
        const int k0 = ig * 256 + kl * 4;
        vf4 w0 = wr[k0], w1 = wr[k0 + 1], w2 = wr[k0 + 2], w3 = wr[k0 + 3];
#pragma unroll
        for (int b = 0; b < 8; ++b) {
          vf4 av = *(const vf4*)&cat1[p0][b][k0];
          acc[b] += av.x * w0; acc[b] += av.y * w1;
          acc[b] += av.z * w2; acc[b] += av.w * w3;
        }
      }
    }

    // ---------- in-wave reduce + finalize layer 1 (registers only) ----------
    {
      vf4 p = reduce8(acc, kl) + bh1p[j];
      float cn  = sigf(p.y) * c1 + sigf(p.x) * tanh_fast(p.z);
      float hn  = sigf(p.w) * tanh_fast(cn);
      float h1n = hn * 0.2f + sp;              // output neuron: h*decay + input(spike)
      c1 = cn;
      if (rep0) {
        // tagged store; consumers at t+1 expect band tagm(t)
        bypass_st(&hx1[p0 * 32768 + g * 4096 + j * 8 + b_loc], h1n + offm);
        if (t == T - 1) {
          // row T-1 never passes through staging: write it directly (once)
          out[(size_t)b_glob * (T * HH) + (size_t)t * HH + j] = h1n;
          out[HOFF + 32768 + b_glob * 512 + j] = h1n;
          out[COFF + 32768 + b_glob * 512 + j] = cn;
        }
      }
    }
    // no trailing barrier: next dot0 reads cat0[p1] (fully written pre-S2);
    // any wave's step-t+1 scatter targets cat0[p0]/cat1[p1] — disjoint from
    // all step-t readers. One-barrier loop cannot accumulate iteration skew.
  }
}

// ---------------- launch ----------------
extern "C" void kernel_launch(void* const* d_in, const int* in_sizes, int n_in,
                              void* d_out, int out_size, void* d_ws, size_t ws_size,
                              hipStream_t stream) {
  const float* x   = (const float*)d_in[0];
  const float* Wx0 = (const float*)d_in[1];
  const float* Wh0 = (const float*)d_in[2];
  const float* bh0 = (const float*)d_in[3];
  const float* Wx1 = (const float*)d_in[4];
  const float* Wh1 = (const float*)d_in[5];
  const float* bh1 = (const float*)d_in[6];
  float* out = (float*)d_out;
  float* ws  = (float*)d_ws;

  float* Wc0p  = ws + WS_WC0;
  float* Wc1p  = ws + WS_WC1;
  float* bh0pf = ws + WS_BH0;
  float* bh1pf = ws + WS_BH1;
  float* hx0   = ws + WS_HX0;
  float* hx1   = ws + WS_HX1;

  // zero both hx0 slots + hx1 slot0 (zeros = no valid band); fill hx1 slot1
  // with 0 + tag1 offset (8.0f) so t=0 reads h1(-1)=0 as already-valid.
  hipMemsetAsync(hx0, 0, 2 * 64 * 512 * sizeof(float), stream);
  hipMemsetAsync(hx1, 0, 64 * 512 * sizeof(float), stream);
  hipMemsetAsync(out + SOFF + BB * HH, 0, BB * HH * sizeof(float), stream);

  pack_wc<<<dim3(512), dim3(256), 0, stream>>>(Wx0, Wh0, 256, 768, Wc0p);
  pack_wc<<<dim3(512), dim3(256), 0, stream>>>(Wx1, Wh1, 512, 1024, Wc1p);
  pack_bias<<<dim3(16), dim3(256), 0, stream>>>(bh0, bh1, bh0pf, bh1pf);
  fill_tag<<<dim3(32), dim3(1024), 0, stream>>>(hx1 + 32768, 8.0f);

  aslstm_main<<<dim3(256), dim3(1024), 0, stream>>>(
      (const vf4*)Wc0p, (const vf4*)Wc1p, (const vf4*)bh0pf, (const vf4*)bh1pf,
      x, hx0, hx1, out);
}